// Round 3
// baseline (372.262 us; speedup 1.0000x reference)
//
#include <hip/hip_runtime.h>

// Performer FAVOR+ causal linear attention, fp32 baseline (r2: sc-pad 69 fix).
// b=2,h=8 -> BH=16 ; n=4096 ; d=64 ; m=256 ; e=64 ; chunk=128 (32 chunks)

constexpr int kBH = 16;
constexpr int kN  = 4096;
constexpr int kD  = 64;
constexpr int kM  = 256;
constexpr int kE  = 64;
constexpr int kC  = 128;
constexpr int kNC = 32;
constexpr float kNorm  = 0.35355339059327373f;  // 64^-0.25
constexpr float kDiagC = 0.0625f;               // 0.5 * 64^-0.5
constexpr float kRatio = 0.0625f;               // 256^-0.5
constexpr float kEpsK  = 1e-4f;
constexpr float kEpsD  = 1e-6f;

// ordered-uint mapping for float atomicMax
__device__ __forceinline__ float dec_max(unsigned u) {
  unsigned b = (u & 0x80000000u) ? (u & 0x7fffffffu) : ~u;
  return __uint_as_float(b);
}

// ---------------------------------------------------------------------------
// K1/K2: dd = norm * (data @ proj^T)  [65536 x 256]
//  IS_Q: phi_q = ratio*(exp(dd - diag - rowmax) + eps)   (stored final)
// !IS_Q: store (dd - diag); atomicMax global per-bh max of dd
// 32 rows/block, 256 threads (thread t owns proj column t, held in VGPRs;
// row data read through block-uniform addresses -> scalar loads).
// ---------------------------------------------------------------------------
template <bool IS_Q>
__global__ __launch_bounds__(256) void k_proj(const float* __restrict__ data,
                                              const float* __restrict__ proj,
                                              float* __restrict__ outv,
                                              unsigned* __restrict__ kmaxU) {
  const int t = threadIdx.x;
  const int lane = t & 63;
  const int wv = t >> 6;
  const long row0 = (long)blockIdx.x * 32;

  float pj[kD];
  {
    const float4* p4 = reinterpret_cast<const float4*>(proj + (long)t * kD);
#pragma unroll
    for (int i = 0; i < kD / 4; ++i) {
      float4 pv = p4[i];
      pj[4 * i + 0] = pv.x; pj[4 * i + 1] = pv.y;
      pj[4 * i + 2] = pv.z; pj[4 * i + 3] = pv.w;
    }
  }

  __shared__ float diagL[32];
  __shared__ float redL[32][4];
  __shared__ float mxL[32];
  __shared__ float wmaxL[4];

  // diag pass: row = t>>3, 8 elems per thread, 8-lane shfl reduce
  {
    const int r = t >> 3, off = (t & 7) * 8;
    const float* dp = data + (row0 + r) * kD + off;
    float ss = 0.f;
#pragma unroll
    for (int u = 0; u < 8; ++u) ss = fmaf(dp[u], dp[u], ss);
    ss += __shfl_xor(ss, 1);
    ss += __shfl_xor(ss, 2);
    ss += __shfl_xor(ss, 4);
    if ((t & 7) == 0) diagL[r] = ss * kDiagC;
  }

  float acc[32];
#pragma unroll
  for (int r = 0; r < 32; ++r) acc[r] = 0.f;

#pragma unroll
  for (int g = 0; g < 8; ++g) {
    const float* rp = data + (row0 + g * 4) * kD;  // block-uniform
#pragma unroll
    for (int kk = 0; kk < kD; ++kk) {
      const float s0 = rp[kk];
      const float s1 = rp[kD + kk];
      const float s2 = rp[2 * kD + kk];
      const float s3 = rp[3 * kD + kk];
      acc[g * 4 + 0] = fmaf(s0, pj[kk], acc[g * 4 + 0]);
      acc[g * 4 + 1] = fmaf(s1, pj[kk], acc[g * 4 + 1]);
      acc[g * 4 + 2] = fmaf(s2, pj[kk], acc[g * 4 + 2]);
      acc[g * 4 + 3] = fmaf(s3, pj[kk], acc[g * 4 + 3]);
    }
  }
#pragma unroll
  for (int r = 0; r < 32; ++r) acc[r] *= kNorm;  // dd

  if (IS_Q) {
#pragma unroll
    for (int r = 0; r < 32; ++r) {
      float m = acc[r];
      m = fmaxf(m, __shfl_xor(m, 1));
      m = fmaxf(m, __shfl_xor(m, 2));
      m = fmaxf(m, __shfl_xor(m, 4));
      m = fmaxf(m, __shfl_xor(m, 8));
      m = fmaxf(m, __shfl_xor(m, 16));
      m = fmaxf(m, __shfl_xor(m, 32));
      if (lane == 0) redL[r][wv] = m;
    }
    __syncthreads();
    if (t < 32)
      mxL[t] = fmaxf(fmaxf(redL[t][0], redL[t][1]), fmaxf(redL[t][2], redL[t][3]));
    __syncthreads();
#pragma unroll
    for (int r = 0; r < 32; ++r) {
      const float val = acc[r] - diagL[r] - mxL[r];
      outv[(row0 + r) * kM + t] = kRatio * (__expf(val) + kEpsK);
    }
  } else {
    __syncthreads();  // diagL ready
    float tm = -3.0e38f;
#pragma unroll
    for (int r = 0; r < 32; ++r) {
      tm = fmaxf(tm, acc[r]);
      outv[(row0 + r) * kM + t] = acc[r] - diagL[r];
    }
    tm = fmaxf(tm, __shfl_xor(tm, 1));
    tm = fmaxf(tm, __shfl_xor(tm, 2));
    tm = fmaxf(tm, __shfl_xor(tm, 4));
    tm = fmaxf(tm, __shfl_xor(tm, 8));
    tm = fmaxf(tm, __shfl_xor(tm, 16));
    tm = fmaxf(tm, __shfl_xor(tm, 32));
    if (lane == 0) wmaxL[wv] = tm;
    __syncthreads();
    if (t == 0) {
      float bm = fmaxf(fmaxf(wmaxL[0], wmaxL[1]), fmaxf(wmaxL[2], wmaxL[3]));
      unsigned ub = __float_as_uint(bm);
      ub = (ub & 0x80000000u) ? ~ub : (ub | 0x80000000u);
      atomicMax(kmaxU + (int)(row0 >> 12), ub);   // row0 / 4096 = bh
    }
  }
}

// ---------------------------------------------------------------------------
// K4: per-chunk sums  S_c[m][e] = sum_rows phik[r][m]*v[r][e],  z_c[m]
// one block per (bh, chunk); thread t owns feature m=t; v via uniform loads.
// ---------------------------------------------------------------------------
__global__ __launch_bounds__(256) void k_chunk(const float* __restrict__ dk,
                                               const float* __restrict__ v,
                                               const unsigned* __restrict__ kmaxU,
                                               float* __restrict__ Sc,
                                               float* __restrict__ zc) {
  const int t = threadIdx.x;
  const int bh = blockIdx.x >> 5;
  const int c = blockIdx.x & 31;
  const float mx = dec_max(kmaxU[bh]);
  const long rowbase = (long)bh * kN + (long)c * kC;
  const float* dkp = dk + rowbase * kM + t;
  const float* vp = v + rowbase * kE;

  float acc[kE];
#pragma unroll
  for (int e = 0; e < kE; ++e) acc[e] = 0.f;
  float zacc = 0.f;

  for (int r = 0; r < kC; ++r) {
    const float ph = kRatio * (__expf(dkp[(long)r * kM] - mx) + kEpsK);
    zacc += ph;
    const float* vr = vp + r * kE;  // block-uniform
#pragma unroll
    for (int e = 0; e < kE; ++e) acc[e] = fmaf(ph, vr[e], acc[e]);
  }

  float* scp = Sc + (long)(bh * kNC + c) * (kM * kE) + (long)t * kE;
#pragma unroll
  for (int e = 0; e < kE; e += 4) {
    float4 o = make_float4(acc[e], acc[e + 1], acc[e + 2], acc[e + 3]);
    *reinterpret_cast<float4*>(scp + e) = o;
  }
  zc[(long)(bh * kNC + c) * kM + t] = zacc;
}

// ---------------------------------------------------------------------------
// K4b: in-place exclusive prefix over the 32 chunks (S and z), per element.
// ---------------------------------------------------------------------------
__global__ __launch_bounds__(256) void k_prefix(float* __restrict__ Sc,
                                                float* __restrict__ zc) {
  const int bh = blockIdx.x / 65;
  const int flat = (blockIdx.x % 65) * 256 + threadIdx.x;
  if (flat < kM * kE) {
    long base = (long)bh * kNC * kM * kE + flat;
    float run = 0.f;
    for (int c = 0; c < kNC; ++c) {
      long idx = base + (long)c * (kM * kE);
      float tmp = Sc[idx];
      Sc[idx] = run;
      run += tmp;
    }
  } else {
    const int m = flat - kM * kE;
    long base = (long)bh * kNC * kM + m;
    float run = 0.f;
    for (int c = 0; c < kNC; ++c) {
      long idx = base + (long)c * kM;
      float tmp = zc[idx];
      zc[idx] = run;
      run += tmp;
    }
  }
}

// ---------------------------------------------------------------------------
// K5: per (bh, chunk):
//   inter  = phi_q @ S_prev                       [128 x 64]
//   scores = tril(phi_q @ phi_k^T)                [128 x 128]
//   intra  = scores @ v                           [128 x 64]
//   denom  = phi_q . (z_prev + eps) + rowsum(scores)
//   out    = (inter + intra) / denom
// Register tile per thread: 8 rows x (8 score cols strided 16 | 4 e cols).
// ---------------------------------------------------------------------------
constexpr int kMT = 32;   // m-tile of the K=256 contraction
constexpr int kPA = 132;  // phiqT pad (b128-aligned; reads conflict-free)
constexpr int kPB = 129;  // phikT pad (b32, conflict-free)
constexpr int kPS = 68;   // S-tile pad (b128-aligned)
constexpr int kPC = 69;   // scores pad: 8*69 mod 32 = 8 -> tr groups 8 banks
                          // apart; writes 2-way (free), reads broadcast-clean.

union SmemU {
  struct {
    float A[kMT][kPA];  // phiqT[mm][r]
    float B[kMT][kPB];  // phikT[mm][r']
    float S[kMT][kPS];  // S_prev tile [mm][e]
  } p1;
  struct {
    float sc[kC][kPC];  // masked scores half [r][k]
  } p2;
};

__global__ __launch_bounds__(256, 2) void k_out(const float* __restrict__ phiq,
                                                const float* __restrict__ dk,
                                                const float* __restrict__ v,
                                                const float* __restrict__ Sc,
                                                const float* __restrict__ zc,
                                                const unsigned* __restrict__ kmaxU,
                                                float* __restrict__ outp) {
  __shared__ __align__(16) SmemU sm;
  __shared__ float sZe[kM];

  const int t = threadIdx.x;
  const int tr = t >> 4;
  const int tc = t & 15;
  const int bh = blockIdx.x >> 5;
  const int c = blockIdx.x & 31;
  const float mx = dec_max(kmaxU[bh]);

  const long row0 = (long)bh * kN + (long)c * kC;
  const float* phiq_p = phiq + row0 * kM;
  const float* dk_p = dk + row0 * kM;
  const float* v_p = v + row0 * kE;
  const float* S_p = Sc + (long)(bh * kNC + c) * (kM * kE);
  const float* z_p = zc + (long)(bh * kNC + c) * kM;

  sZe[t] = z_p[t] + kEpsD;

  const int r0 = tr * 8;
  const int e0 = tc * 4;

  float scA[8][8];
  float inter_[8][4];
  float dena[8];
#pragma unroll
  for (int i = 0; i < 8; ++i) {
    dena[i] = 0.f;
#pragma unroll
    for (int j = 0; j < 8; ++j) scA[i][j] = 0.f;
#pragma unroll
    for (int j = 0; j < 4; ++j) inter_[i][j] = 0.f;
  }

  for (int mt = 0; mt < kM / kMT; ++mt) {
    __syncthreads();
    // stage phiqT
#pragma unroll
    for (int i = 0; i < (kC * kMT) / 256; ++i) {
      int flat = i * 256 + t;
      int rr = flat >> 5;
      int mm = flat & 31;
      sm.p1.A[mm][rr] = phiq_p[(long)rr * kM + mt * kMT + mm];
    }
    // stage phikT (exp transform on the fly)
#pragma unroll
    for (int i = 0; i < (kC * kMT) / 256; ++i) {
      int flat = i * 256 + t;
      int rr = flat >> 5;
      int mm = flat & 31;
      float x = dk_p[(long)rr * kM + mt * kMT + mm];
      sm.p1.B[mm][rr] = kRatio * (__expf(x - mx) + kEpsK);
    }
    // stage S_prev tile
#pragma unroll
    for (int i = 0; i < (kMT * kE) / 256; ++i) {
      int flat = i * 256 + t;
      int mm = flat >> 6;
      int e = flat & 63;
      sm.p1.S[mm][e] = S_p[(long)(mt * kMT + mm) * kE + e];
    }
    __syncthreads();

#pragma unroll 2
    for (int mm = 0; mm < kMT; ++mm) {
      float a[8];
      float4 a0 = *reinterpret_cast<const float4*>(&sm.p1.A[mm][r0]);
      float4 a1 = *reinterpret_cast<const float4*>(&sm.p1.A[mm][r0 + 4]);
      a[0] = a0.x; a[1] = a0.y; a[2] = a0.z; a[3] = a0.w;
      a[4] = a1.x; a[5] = a1.y; a[6] = a1.z; a[7] = a1.w;
      float b[8];
#pragma unroll
      for (int j = 0; j < 8; ++j) b[j] = sm.p1.B[mm][tc + 16 * j];
      float4 sv = *reinterpret_cast<const float4*>(&sm.p1.S[mm][e0]);
      float ze = sZe[mt * kMT + mm];
#pragma unroll
      for (int i = 0; i < 8; ++i) {
        dena[i] = fmaf(a[i], ze, dena[i]);
#pragma unroll
        for (int j = 0; j < 8; ++j) scA[i][j] = fmaf(a[i], b[j], scA[i][j]);
        inter_[i][0] = fmaf(a[i], sv.x, inter_[i][0]);
        inter_[i][1] = fmaf(a[i], sv.y, inter_[i][1]);
        inter_[i][2] = fmaf(a[i], sv.z, inter_[i][2]);
        inter_[i][3] = fmaf(a[i], sv.w, inter_[i][3]);
      }
    }
  }

  float intra_[8][4];
  float denb[8];
#pragma unroll
  for (int i = 0; i < 8; ++i) {
    denb[i] = 0.f;
#pragma unroll
    for (int j = 0; j < 4; ++j) intra_[i][j] = 0.f;
  }

#pragma unroll
  for (int half = 0; half < 2; ++half) {
    __syncthreads();
    // write this half's masked score columns to LDS
#pragma unroll
    for (int i = 0; i < 8; ++i) {
      const int r = r0 + i;
#pragma unroll
      for (int jj = 0; jj < 4; ++jj) {
        const int j = half * 4 + jj;
        const int cg = tc + 16 * j;
        sm.p2.sc[r][tc + 16 * jj] = (cg <= r) ? scA[i][j] : 0.f;
      }
    }
    __syncthreads();
    const float* vh = v_p + (long)half * 64 * kE;
    for (int k2 = 0; k2 < 64; ++k2) {
      float as[8];
#pragma unroll
      for (int i = 0; i < 8; ++i) as[i] = sm.p2.sc[r0 + i][k2];
      const float4 vv = *reinterpret_cast<const float4*>(vh + (long)k2 * kE + e0);
#pragma unroll
      for (int i = 0; i < 8; ++i) {
        denb[i] += as[i];
        intra_[i][0] = fmaf(as[i], vv.x, intra_[i][0]);
        intra_[i][1] = fmaf(as[i], vv.y, intra_[i][1]);
        intra_[i][2] = fmaf(as[i], vv.z, intra_[i][2]);
        intra_[i][3] = fmaf(as[i], vv.w, intra_[i][3]);
      }
    }
  }

  float* op = outp + row0 * kE;
#pragma unroll
  for (int i = 0; i < 8; ++i) {
    const float dinv = 1.0f / (dena[i] + denb[i]);
    float4 o;
    o.x = (inter_[i][0] + intra_[i][0]) * dinv;
    o.y = (inter_[i][1] + intra_[i][1]) * dinv;
    o.z = (inter_[i][2] + intra_[i][2]) * dinv;
    o.w = (inter_[i][3] + intra_[i][3]) * dinv;
    *reinterpret_cast<float4*>(op + (long)(r0 + i) * kE + e0) = o;
  }
}

// ---------------------------------------------------------------------------
extern "C" void kernel_launch(void* const* d_in, const int* in_sizes, int n_in,
                              void* d_out, int out_size, void* d_ws, size_t ws_size,
                              hipStream_t stream) {
  const float* q = (const float*)d_in[0];
  const float* k = (const float*)d_in[1];
  const float* v = (const float*)d_in[2];
  const float* proj = (const float*)d_in[3];
  float* out = (float*)d_out;
  float* ws = (float*)d_ws;

  // ws layout (floats):
  float* phiq = ws;                          // 16,777,216  (final phi_q)
  float* dkb = ws + 16777216L;               // 16,777,216  (dd - diag for k)
  float* Sc = ws + 33554432L;                // 8,388,608   (chunk S -> excl prefix)
  float* zc = ws + 41943040L;                // 131,072     (chunk z -> excl prefix)
  unsigned* kmaxU = (unsigned*)(ws + 42074112L);  // 16 (ordered-uint max per bh)

  hipMemsetAsync(kmaxU, 0, kBH * sizeof(unsigned), stream);
  k_proj<true><<<dim3(2048), dim3(256), 0, stream>>>(q, proj, phiq, nullptr);
  k_proj<false><<<dim3(2048), dim3(256), 0, stream>>>(k, proj, dkb, kmaxU);
  k_chunk<<<dim3(512), dim3(256), 0, stream>>>(dkb, v, kmaxU, Sc, zc);
  k_prefix<<<dim3(16 * 65), dim3(256), 0, stream>>>(Sc, zc);
  k_out<<<dim3(512), dim3(256), 0, stream>>>(phiq, dkb, v, Sc, zc, kmaxU, out);
}

// Round 5
// 336.331 us; speedup vs baseline: 1.1068x; 1.1068x over previous
//
#include <hip/hip_runtime.h>

// Performer FAVOR+ causal linear attention.
// r5 == r4 resubmit: register-tiled k_proj / k_chunk (kill uniform-load
// issue-bound pattern); k_out & k_prefix unchanged from r3 (passing, 124.5us).
// b=2,h=8 -> BH=16 ; n=4096 ; d=64 ; m=256 ; e=64 ; chunk=128 (32 chunks)

constexpr int kBH = 16;
constexpr int kN  = 4096;
constexpr int kD  = 64;
constexpr int kM  = 256;
constexpr int kE  = 64;
constexpr int kC  = 128;
constexpr int kNC = 32;
constexpr float kNorm  = 0.35355339059327373f;  // 64^-0.25
constexpr float kDiagC = 0.0625f;               // 0.5 * 64^-0.5
constexpr float kRatio = 0.0625f;               // 256^-0.5
constexpr float kEpsK  = 1e-4f;
constexpr float kEpsD  = 1e-6f;

// ordered-uint mapping for float atomicMax
__device__ __forceinline__ float dec_max(unsigned u) {
  unsigned b = (u & 0x80000000u) ? (u & 0x7fffffffu) : ~u;
  return __uint_as_float(b);
}

// ---------------------------------------------------------------------------
// K1/K2: dd = norm*(data @ proj^T) [65536 x 256], register-tiled GEMM.
// Block: 64 rows x 256 cols, K=64 staged in 4 tiles of 16.
// Thread (t): cols m0=4*(t&63) (b128-contiguous), rows r0=16*(t>>6)
// (wave-uniform -> broadcast LDS reads). 16x4 acc tile, 64 FMA / 5 b128.
//  IS_Q: phi_q = ratio*(exp(dd - diag - rowmax) + eps)  (stored final)
// !IS_Q: store (dd - diag); atomicMax global per-bh max of dd
// ---------------------------------------------------------------------------
template <bool IS_Q>
__global__ __launch_bounds__(256, 3) void k_proj(const float* __restrict__ data,
                                                 const float* __restrict__ proj,
                                                 float* __restrict__ outv,
                                                 unsigned* __restrict__ kmaxU) {
  __shared__ __align__(16) float dT[16][68];     // [k][row]  (transposed)
  __shared__ __align__(16) float pT[16][260];    // [k][m]    (transposed)
  __shared__ float diagL[64];
  __shared__ float wmaxL[4];

  const int t = threadIdx.x;
  const int j = t & 63;        // col group: m0 = 4j
  const int w = t >> 6;        // wave: rows r0 = 16w
  const int r0 = 16 * w;
  const long row0 = (long)blockIdx.x * 64;

  // diag: row r = t>>2, 16 elems per thread, 4-lane reduce
  {
    const int r = t >> 2, off = (t & 3) * 16;
    const float* dp = data + (row0 + r) * kD + off;
    float ss = 0.f;
#pragma unroll
    for (int u = 0; u < 4; ++u) {
      float4 dv = *reinterpret_cast<const float4*>(dp + 4 * u);
      ss = fmaf(dv.x, dv.x, ss); ss = fmaf(dv.y, dv.y, ss);
      ss = fmaf(dv.z, dv.z, ss); ss = fmaf(dv.w, dv.w, ss);
    }
    ss += __shfl_xor(ss, 1);
    ss += __shfl_xor(ss, 2);
    if ((t & 3) == 0) diagL[r] = ss * kDiagC;
  }

  float acc[16][4];
#pragma unroll
  for (int i = 0; i < 16; ++i)
#pragma unroll
    for (int u = 0; u < 4; ++u) acc[i][u] = 0.f;

  for (int kt = 0; kt < 4; ++kt) {
    __syncthreads();  // also covers diagL for the epilogue
    // stage dT[k][row]: one float4 per thread
    {
      const int row = t >> 2, k4 = (t & 3) * 4;
      float4 dv = *reinterpret_cast<const float4*>(
          &data[(row0 + row) * kD + kt * 16 + k4]);
      dT[k4 + 0][row] = dv.x; dT[k4 + 1][row] = dv.y;
      dT[k4 + 2][row] = dv.z; dT[k4 + 3][row] = dv.w;
    }
    // stage pT[k][m]: 4 float4 per thread
#pragma unroll
    for (int i = 0; i < 4; ++i) {
      const int flat = i * 256 + t;
      const int m = flat >> 2, k4 = (flat & 3) * 4;
      float4 pv = *reinterpret_cast<const float4*>(
          &proj[(long)m * kD + kt * 16 + k4]);
      pT[k4 + 0][m] = pv.x; pT[k4 + 1][m] = pv.y;
      pT[k4 + 2][m] = pv.z; pT[k4 + 3][m] = pv.w;
    }
    __syncthreads();

#pragma unroll 4
    for (int kk = 0; kk < 16; ++kk) {
      float4 b = *reinterpret_cast<const float4*>(&pT[kk][4 * j]);
      float a[16];
#pragma unroll
      for (int g = 0; g < 4; ++g) {
        float4 av = *reinterpret_cast<const float4*>(&dT[kk][r0 + 4 * g]);
        a[4 * g + 0] = av.x; a[4 * g + 1] = av.y;
        a[4 * g + 2] = av.z; a[4 * g + 3] = av.w;
      }
#pragma unroll
      for (int i = 0; i < 16; ++i) {
        acc[i][0] = fmaf(a[i], b.x, acc[i][0]);
        acc[i][1] = fmaf(a[i], b.y, acc[i][1]);
        acc[i][2] = fmaf(a[i], b.z, acc[i][2]);
        acc[i][3] = fmaf(a[i], b.w, acc[i][3]);
      }
    }
  }

#pragma unroll
  for (int i = 0; i < 16; ++i)
#pragma unroll
    for (int u = 0; u < 4; ++u) acc[i][u] *= kNorm;  // dd

  if (IS_Q) {
#pragma unroll
    for (int i = 0; i < 16; ++i) {
      float m2 = fmaxf(fmaxf(acc[i][0], acc[i][1]), fmaxf(acc[i][2], acc[i][3]));
      m2 = fmaxf(m2, __shfl_xor(m2, 1));
      m2 = fmaxf(m2, __shfl_xor(m2, 2));
      m2 = fmaxf(m2, __shfl_xor(m2, 4));
      m2 = fmaxf(m2, __shfl_xor(m2, 8));
      m2 = fmaxf(m2, __shfl_xor(m2, 16));
      m2 = fmaxf(m2, __shfl_xor(m2, 32));
      const float dg = diagL[r0 + i];
      float4 o;
      o.x = kRatio * (__expf(acc[i][0] - dg - m2) + kEpsK);
      o.y = kRatio * (__expf(acc[i][1] - dg - m2) + kEpsK);
      o.z = kRatio * (__expf(acc[i][2] - dg - m2) + kEpsK);
      o.w = kRatio * (__expf(acc[i][3] - dg - m2) + kEpsK);
      *reinterpret_cast<float4*>(&outv[(row0 + r0 + i) * kM + 4 * j]) = o;
    }
  } else {
    float bm = -3.0e38f;
#pragma unroll
    for (int i = 0; i < 16; ++i) {
      const float dg = diagL[r0 + i];
      bm = fmaxf(bm, fmaxf(fmaxf(acc[i][0], acc[i][1]),
                           fmaxf(acc[i][2], acc[i][3])));
      float4 o;
      o.x = acc[i][0] - dg; o.y = acc[i][1] - dg;
      o.z = acc[i][2] - dg; o.w = acc[i][3] - dg;
      *reinterpret_cast<float4*>(&outv[(row0 + r0 + i) * kM + 4 * j]) = o;
    }
    bm = fmaxf(bm, __shfl_xor(bm, 1));
    bm = fmaxf(bm, __shfl_xor(bm, 2));
    bm = fmaxf(bm, __shfl_xor(bm, 4));
    bm = fmaxf(bm, __shfl_xor(bm, 8));
    bm = fmaxf(bm, __shfl_xor(bm, 16));
    bm = fmaxf(bm, __shfl_xor(bm, 32));
    if ((t & 63) == 0) wmaxL[w] = bm;
    __syncthreads();
    if (t == 0) {
      float b2 = fmaxf(fmaxf(wmaxL[0], wmaxL[1]), fmaxf(wmaxL[2], wmaxL[3]));
      unsigned ub = __float_as_uint(b2);
      ub = (ub & 0x80000000u) ? ~ub : (ub | 0x80000000u);
      atomicMax(kmaxU + (int)(row0 >> 12), ub);
    }
  }
}

// ---------------------------------------------------------------------------
// K4: per-chunk sums  S_c[m][e], z_c[m].  Register-tiled outer product:
// thread owns 16 m (m0=16*(t>>4)) x 4 e (e0=4*(t&15)); r staged in tiles
// of 16 with exp'd phi in swizzled LDS (spreads stride-64B b128 reads).
// ---------------------------------------------------------------------------
__device__ __forceinline__ int phi_col(int m) { return m + 4 * ((m >> 4) & 7); }

__global__ __launch_bounds__(256, 2) void k_chunk(const float* __restrict__ dk,
                                                  const float* __restrict__ v,
                                                  const unsigned* __restrict__ kmaxU,
                                                  float* __restrict__ Sc,
                                                  float* __restrict__ zc) {
  __shared__ __align__(16) float phE[16][284];  // swizzled cols (max 283)
  __shared__ __align__(16) float vT[16][68];

  const int t = threadIdx.x;
  const int bh = blockIdx.x >> 5;
  const int c = blockIdx.x & 31;
  const float mx = dec_max(kmaxU[bh]);
  const long rowbase = (long)bh * kN + (long)c * kC;
  const float* dkp = dk + rowbase * kM;
  const float* vp = v + rowbase * kE;

  const int et = t & 15, mg = t >> 4;
  const int e0 = 4 * et, m0 = 16 * mg;
  const int pcol = phi_col(m0);  // = m0 + 4*(mg&7)

  float acc[16][4];
#pragma unroll
  for (int i = 0; i < 16; ++i)
#pragma unroll
    for (int u = 0; u < 4; ++u) acc[i][u] = 0.f;
  float zsum = 0.f;

  for (int rt = 0; rt < 8; ++rt) {
    __syncthreads();
    // stage phi (exp on the fly), swizzled columns
#pragma unroll
    for (int i = 0; i < 4; ++i) {
      const int flat = i * 256 + t;
      const int rr = flat >> 6;
      const int m4 = (flat & 63) * 4;
      float4 xx = *reinterpret_cast<const float4*>(
          &dkp[(long)(rt * 16 + rr) * kM + m4]);
      float4 ph;
      ph.x = kRatio * (__expf(xx.x - mx) + kEpsK);
      ph.y = kRatio * (__expf(xx.y - mx) + kEpsK);
      ph.z = kRatio * (__expf(xx.z - mx) + kEpsK);
      ph.w = kRatio * (__expf(xx.w - mx) + kEpsK);
      *reinterpret_cast<float4*>(&phE[rr][phi_col(m4)]) = ph;
    }
    // stage v tile
    {
      const int rr = t >> 4, ee = (t & 15) * 4;
      float4 vv = *reinterpret_cast<const float4*>(
          &vp[(long)(rt * 16 + rr) * kE + ee]);
      *reinterpret_cast<float4*>(&vT[rr][ee]) = vv;
    }
    __syncthreads();

    for (int r = 0; r < 16; ++r) {
      float4 bv = *reinterpret_cast<const float4*>(&vT[r][e0]);
      float pv[16];
#pragma unroll
      for (int a = 0; a < 4; ++a) {
        float4 p4 = *reinterpret_cast<const float4*>(&phE[r][pcol + 4 * a]);
        pv[4 * a + 0] = p4.x; pv[4 * a + 1] = p4.y;
        pv[4 * a + 2] = p4.z; pv[4 * a + 3] = p4.w;
      }
#pragma unroll
      for (int i = 0; i < 16; ++i) {
        acc[i][0] = fmaf(pv[i], bv.x, acc[i][0]);
        acc[i][1] = fmaf(pv[i], bv.y, acc[i][1]);
        acc[i][2] = fmaf(pv[i], bv.z, acc[i][2]);
        acc[i][3] = fmaf(pv[i], bv.w, acc[i][3]);
      }
    }
    // z partial: thread t owns feature column m=t
    {
      const int zcol = phi_col(t);
      float zp = 0.f;
#pragma unroll
      for (int r = 0; r < 16; ++r) zp += phE[r][zcol];
      zsum += zp;
    }
  }

  float* scp = Sc + (long)(bh * kNC + c) * (kM * kE);
#pragma unroll
  for (int i = 0; i < 16; ++i) {
    float4 o = make_float4(acc[i][0], acc[i][1], acc[i][2], acc[i][3]);
    *reinterpret_cast<float4*>(&scp[(long)(m0 + i) * kE + e0]) = o;
  }
  zc[(long)(bh * kNC + c) * kM + t] = zsum;
}

// ---------------------------------------------------------------------------
// K4b: in-place exclusive prefix over the 32 chunks (S and z), per element.
// ---------------------------------------------------------------------------
__global__ __launch_bounds__(256) void k_prefix(float* __restrict__ Sc,
                                                float* __restrict__ zc) {
  const int bh = blockIdx.x / 65;
  const int flat = (blockIdx.x % 65) * 256 + threadIdx.x;
  if (flat < kM * kE) {
    long base = (long)bh * kNC * kM * kE + flat;
    float run = 0.f;
    for (int c = 0; c < kNC; ++c) {
      long idx = base + (long)c * (kM * kE);
      float tmp = Sc[idx];
      Sc[idx] = run;
      run += tmp;
    }
  } else {
    const int m = flat - kM * kE;
    long base = (long)bh * kNC * kM + m;
    float run = 0.f;
    for (int c = 0; c < kNC; ++c) {
      long idx = base + (long)c * kM;
      float tmp = zc[idx];
      zc[idx] = run;
      run += tmp;
    }
  }
}

// ---------------------------------------------------------------------------
// K5 (unchanged from r3): per (bh, chunk) fused inter/intra/denom/out.
// ---------------------------------------------------------------------------
constexpr int kMT = 32;   // m-tile of the K=256 contraction
constexpr int kPA = 132;  // phiqT pad (b128-aligned; reads conflict-free)
constexpr int kPB = 129;  // phikT pad (b32, conflict-free)
constexpr int kPS = 68;   // S-tile pad (b128-aligned)
constexpr int kPC = 69;   // scores pad

union SmemU {
  struct {
    float A[kMT][kPA];  // phiqT[mm][r]
    float B[kMT][kPB];  // phikT[mm][r']
    float S[kMT][kPS];  // S_prev tile [mm][e]
  } p1;
  struct {
    float sc[kC][kPC];  // masked scores half [r][k]
  } p2;
};

__global__ __launch_bounds__(256, 2) void k_out(const float* __restrict__ phiq,
                                                const float* __restrict__ dk,
                                                const float* __restrict__ v,
                                                const float* __restrict__ Sc,
                                                const float* __restrict__ zc,
                                                const unsigned* __restrict__ kmaxU,
                                                float* __restrict__ outp) {
  __shared__ __align__(16) SmemU sm;
  __shared__ float sZe[kM];

  const int t = threadIdx.x;
  const int tr = t >> 4;
  const int tc = t & 15;
  const int bh = blockIdx.x >> 5;
  const int c = blockIdx.x & 31;
  const float mx = dec_max(kmaxU[bh]);

  const long row0 = (long)bh * kN + (long)c * kC;
  const float* phiq_p = phiq + row0 * kM;
  const float* dk_p = dk + row0 * kM;
  const float* v_p = v + row0 * kE;
  const float* S_p = Sc + (long)(bh * kNC + c) * (kM * kE);
  const float* z_p = zc + (long)(bh * kNC + c) * kM;

  sZe[t] = z_p[t] + kEpsD;

  const int r0 = tr * 8;
  const int e0 = tc * 4;

  float scA[8][8];
  float inter_[8][4];
  float dena[8];
#pragma unroll
  for (int i = 0; i < 8; ++i) {
    dena[i] = 0.f;
#pragma unroll
    for (int j = 0; j < 8; ++j) scA[i][j] = 0.f;
#pragma unroll
    for (int j = 0; j < 4; ++j) inter_[i][j] = 0.f;
  }

  for (int mt = 0; mt < kM / kMT; ++mt) {
    __syncthreads();
    // stage phiqT
#pragma unroll
    for (int i = 0; i < (kC * kMT) / 256; ++i) {
      int flat = i * 256 + t;
      int rr = flat >> 5;
      int mm = flat & 31;
      sm.p1.A[mm][rr] = phiq_p[(long)rr * kM + mt * kMT + mm];
    }
    // stage phikT (exp transform on the fly)
#pragma unroll
    for (int i = 0; i < (kC * kMT) / 256; ++i) {
      int flat = i * 256 + t;
      int rr = flat >> 5;
      int mm = flat & 31;
      float x = dk_p[(long)rr * kM + mt * kMT + mm];
      sm.p1.B[mm][rr] = kRatio * (__expf(x - mx) + kEpsK);
    }
    // stage S_prev tile
#pragma unroll
    for (int i = 0; i < (kMT * kE) / 256; ++i) {
      int flat = i * 256 + t;
      int mm = flat >> 6;
      int e = flat & 63;
      sm.p1.S[mm][e] = S_p[(long)(mt * kMT + mm) * kE + e];
    }
    __syncthreads();

#pragma unroll 2
    for (int mm = 0; mm < kMT; ++mm) {
      float a[8];
      float4 a0 = *reinterpret_cast<const float4*>(&sm.p1.A[mm][r0]);
      float4 a1 = *reinterpret_cast<const float4*>(&sm.p1.A[mm][r0 + 4]);
      a[0] = a0.x; a[1] = a0.y; a[2] = a0.z; a[3] = a0.w;
      a[4] = a1.x; a[5] = a1.y; a[6] = a1.z; a[7] = a1.w;
      float b[8];
#pragma unroll
      for (int j = 0; j < 8; ++j) b[j] = sm.p1.B[mm][tc + 16 * j];
      float4 sv = *reinterpret_cast<const float4*>(&sm.p1.S[mm][e0]);
      float ze = sZe[mt * kMT + mm];
#pragma unroll
      for (int i = 0; i < 8; ++i) {
        dena[i] = fmaf(a[i], ze, dena[i]);
#pragma unroll
        for (int j = 0; j < 8; ++j) scA[i][j] = fmaf(a[i], b[j], scA[i][j]);
        inter_[i][0] = fmaf(a[i], sv.x, inter_[i][0]);
        inter_[i][1] = fmaf(a[i], sv.y, inter_[i][1]);
        inter_[i][2] = fmaf(a[i], sv.z, inter_[i][2]);
        inter_[i][3] = fmaf(a[i], sv.w, inter_[i][3]);
      }
    }
  }

  float intra_[8][4];
  float denb[8];
#pragma unroll
  for (int i = 0; i < 8; ++i) {
    denb[i] = 0.f;
#pragma unroll
    for (int j = 0; j < 4; ++j) intra_[i][j] = 0.f;
  }

#pragma unroll
  for (int half = 0; half < 2; ++half) {
    __syncthreads();
    // write this half's masked score columns to LDS
#pragma unroll
    for (int i = 0; i < 8; ++i) {
      const int r = r0 + i;
#pragma unroll
      for (int jj = 0; jj < 4; ++jj) {
        const int j = half * 4 + jj;
        const int cg = tc + 16 * j;
        sm.p2.sc[r][tc + 16 * jj] = (cg <= r) ? scA[i][j] : 0.f;
      }
    }
    __syncthreads();
    const float* vh = v_p + (long)half * 64 * kE;
    for (int k2 = 0; k2 < 64; ++k2) {
      float as[8];
#pragma unroll
      for (int i = 0; i < 8; ++i) as[i] = sm.p2.sc[r0 + i][k2];
      const float4 vv = *reinterpret_cast<const float4*>(vh + (long)k2 * kE + e0);
#pragma unroll
      for (int i = 0; i < 8; ++i) {
        denb[i] += as[i];
        intra_[i][0] = fmaf(as[i], vv.x, intra_[i][0]);
        intra_[i][1] = fmaf(as[i], vv.y, intra_[i][1]);
        intra_[i][2] = fmaf(as[i], vv.z, intra_[i][2]);
        intra_[i][3] = fmaf(as[i], vv.w, intra_[i][3]);
      }
    }
  }

  float* op = outp + row0 * kE;
#pragma unroll
  for (int i = 0; i < 8; ++i) {
    const float dinv = 1.0f / (dena[i] + denb[i]);
    float4 o;
    o.x = (inter_[i][0] + intra_[i][0]) * dinv;
    o.y = (inter_[i][1] + intra_[i][1]) * dinv;
    o.z = (inter_[i][2] + intra_[i][2]) * dinv;
    o.w = (inter_[i][3] + intra_[i][3]) * dinv;
    *reinterpret_cast<float4*>(op + (long)(r0 + i) * kE + e0) = o;
  }
}

// ---------------------------------------------------------------------------
extern "C" void kernel_launch(void* const* d_in, const int* in_sizes, int n_in,
                              void* d_out, int out_size, void* d_ws, size_t ws_size,
                              hipStream_t stream) {
  const float* q = (const float*)d_in[0];
  const float* k = (const float*)d_in[1];
  const float* v = (const float*)d_in[2];
  const float* proj = (const float*)d_in[3];
  float* out = (float*)d_out;
  float* ws = (float*)d_ws;

  // ws layout (floats):
  float* phiq = ws;                          // 16,777,216  (final phi_q)
  float* dkb = ws + 16777216L;               // 16,777,216  (dd - diag for k)
  float* Sc = ws + 33554432L;                // 8,388,608   (chunk S -> excl prefix)
  float* zc = ws + 41943040L;                // 131,072     (chunk z -> excl prefix)
  unsigned* kmaxU = (unsigned*)(ws + 42074112L);  // 16 (ordered-uint max per bh)

  hipMemsetAsync(kmaxU, 0, kBH * sizeof(unsigned), stream);
  k_proj<true><<<dim3(1024), dim3(256), 0, stream>>>(q, proj, phiq, nullptr);
  k_proj<false><<<dim3(1024), dim3(256), 0, stream>>>(k, proj, dkb, kmaxU);
  k_chunk<<<dim3(512), dim3(256), 0, stream>>>(dkb, v, kmaxU, Sc, zc);
  k_prefix<<<dim3(16 * 65), dim3(256), 0, stream>>>(Sc, zc);
  k_out<<<dim3(512), dim3(256), 0, stream>>>(phiq, dkb, v, Sc, zc, kmaxU, out);
}

// Round 6
// 263.830 us; speedup vs baseline: 1.4110x; 1.2748x over previous
//
#include <hip/hip_runtime.h>

// Performer FAVOR+ causal linear attention.
// r6: k_out phase-1 -> split-bf16 MFMA (scores+inter+den); phase-2 (intra)
//     kept as r5's verified fp32 VALU code. k_proj<false> stores E=exp(dd-diag)
//     (exp -> fma downstream). k_prefix float4. k_proj/k_chunk tiling = r5.
// b=2,h=8 -> BH=16 ; n=4096 ; d=64 ; m=256 ; e=64 ; chunk=128 (32 chunks)

constexpr int kBH = 16;
constexpr int kN  = 4096;
constexpr int kD  = 64;
constexpr int kM  = 256;
constexpr int kE  = 64;
constexpr int kC  = 128;
constexpr int kNC = 32;
constexpr float kNorm  = 0.35355339059327373f;  // 64^-0.25
constexpr float kDiagC = 0.0625f;               // 0.5 * 64^-0.5
constexpr float kRatio = 0.0625f;               // 256^-0.5
constexpr float kEpsK  = 1e-4f;
constexpr float kEpsD  = 1e-6f;

typedef short s8v __attribute__((ext_vector_type(8)));   // 8 bf16 (4 VGPR)
typedef float f4v __attribute__((ext_vector_type(4)));   // MFMA acc

__device__ __forceinline__ float dec_max(unsigned u) {
  unsigned b = (u & 0x80000000u) ? (u & 0x7fffffffu) : ~u;
  return __uint_as_float(b);
}
__device__ __forceinline__ unsigned short f2bf(float x) {
  unsigned u = __float_as_uint(x);
  return (unsigned short)((u + 0x7FFFu + ((u >> 16) & 1u)) >> 16);
}
__device__ __forceinline__ float bf2f(unsigned short b) {
  return __uint_as_float(((unsigned)b) << 16);
}

// ---------------------------------------------------------------------------
// K1/K2: dd = norm*(data @ proj^T), register-tiled GEMM (validated r5).
//  IS_Q: phi_q stored final.   !IS_Q: store E = exp(dd - diag); atomicMax dd.
// ---------------------------------------------------------------------------
template <bool IS_Q>
__global__ __launch_bounds__(256, 3) void k_proj(const float* __restrict__ data,
                                                 const float* __restrict__ proj,
                                                 float* __restrict__ outv,
                                                 unsigned* __restrict__ kmaxU) {
  __shared__ __align__(16) float dT[16][68];     // [k][row]
  __shared__ __align__(16) float pT[16][260];    // [k][m]
  __shared__ float diagL[64];
  __shared__ float wmaxL[4];

  const int t = threadIdx.x;
  const int j = t & 63;
  const int w = t >> 6;
  const int r0 = 16 * w;
  const long row0 = (long)blockIdx.x * 64;

  {
    const int r = t >> 2, off = (t & 3) * 16;
    const float* dp = data + (row0 + r) * kD + off;
    float ss = 0.f;
#pragma unroll
    for (int u = 0; u < 4; ++u) {
      float4 dv = *reinterpret_cast<const float4*>(dp + 4 * u);
      ss = fmaf(dv.x, dv.x, ss); ss = fmaf(dv.y, dv.y, ss);
      ss = fmaf(dv.z, dv.z, ss); ss = fmaf(dv.w, dv.w, ss);
    }
    ss += __shfl_xor(ss, 1);
    ss += __shfl_xor(ss, 2);
    if ((t & 3) == 0) diagL[r] = ss * kDiagC;
  }

  float acc[16][4];
#pragma unroll
  for (int i = 0; i < 16; ++i)
#pragma unroll
    for (int u = 0; u < 4; ++u) acc[i][u] = 0.f;

  for (int kt = 0; kt < 4; ++kt) {
    __syncthreads();
    {
      const int row = t >> 2, k4 = (t & 3) * 4;
      float4 dv = *reinterpret_cast<const float4*>(
          &data[(row0 + row) * kD + kt * 16 + k4]);
      dT[k4 + 0][row] = dv.x; dT[k4 + 1][row] = dv.y;
      dT[k4 + 2][row] = dv.z; dT[k4 + 3][row] = dv.w;
    }
#pragma unroll
    for (int i = 0; i < 4; ++i) {
      const int flat = i * 256 + t;
      const int m = flat >> 2, k4 = (flat & 3) * 4;
      float4 pv = *reinterpret_cast<const float4*>(
          &proj[(long)m * kD + kt * 16 + k4]);
      pT[k4 + 0][m] = pv.x; pT[k4 + 1][m] = pv.y;
      pT[k4 + 2][m] = pv.z; pT[k4 + 3][m] = pv.w;
    }
    __syncthreads();

#pragma unroll 4
    for (int kk = 0; kk < 16; ++kk) {
      float4 b = *reinterpret_cast<const float4*>(&pT[kk][4 * j]);
      float a[16];
#pragma unroll
      for (int g = 0; g < 4; ++g) {
        float4 av = *reinterpret_cast<const float4*>(&dT[kk][r0 + 4 * g]);
        a[4 * g + 0] = av.x; a[4 * g + 1] = av.y;
        a[4 * g + 2] = av.z; a[4 * g + 3] = av.w;
      }
#pragma unroll
      for (int i = 0; i < 16; ++i) {
        acc[i][0] = fmaf(a[i], b.x, acc[i][0]);
        acc[i][1] = fmaf(a[i], b.y, acc[i][1]);
        acc[i][2] = fmaf(a[i], b.z, acc[i][2]);
        acc[i][3] = fmaf(a[i], b.w, acc[i][3]);
      }
    }
  }

#pragma unroll
  for (int i = 0; i < 16; ++i)
#pragma unroll
    for (int u = 0; u < 4; ++u) acc[i][u] *= kNorm;  // dd

  if (IS_Q) {
#pragma unroll
    for (int i = 0; i < 16; ++i) {
      float m2 = fmaxf(fmaxf(acc[i][0], acc[i][1]), fmaxf(acc[i][2], acc[i][3]));
      m2 = fmaxf(m2, __shfl_xor(m2, 1));
      m2 = fmaxf(m2, __shfl_xor(m2, 2));
      m2 = fmaxf(m2, __shfl_xor(m2, 4));
      m2 = fmaxf(m2, __shfl_xor(m2, 8));
      m2 = fmaxf(m2, __shfl_xor(m2, 16));
      m2 = fmaxf(m2, __shfl_xor(m2, 32));
      const float dg = diagL[r0 + i];
      float4 o;
      o.x = kRatio * (__expf(acc[i][0] - dg - m2) + kEpsK);
      o.y = kRatio * (__expf(acc[i][1] - dg - m2) + kEpsK);
      o.z = kRatio * (__expf(acc[i][2] - dg - m2) + kEpsK);
      o.w = kRatio * (__expf(acc[i][3] - dg - m2) + kEpsK);
      *reinterpret_cast<float4*>(&outv[(row0 + r0 + i) * kM + 4 * j]) = o;
    }
  } else {
    float bm = -3.0e38f;
#pragma unroll
    for (int i = 0; i < 16; ++i) {
      const float dg = diagL[r0 + i];
      bm = fmaxf(bm, fmaxf(fmaxf(acc[i][0], acc[i][1]),
                           fmaxf(acc[i][2], acc[i][3])));
      float4 o;  // E = exp(dd - diag); range-safe (dd-diag <= ~22)
      o.x = __expf(acc[i][0] - dg); o.y = __expf(acc[i][1] - dg);
      o.z = __expf(acc[i][2] - dg); o.w = __expf(acc[i][3] - dg);
      *reinterpret_cast<float4*>(&outv[(row0 + r0 + i) * kM + 4 * j]) = o;
    }
    bm = fmaxf(bm, __shfl_xor(bm, 1));
    bm = fmaxf(bm, __shfl_xor(bm, 2));
    bm = fmaxf(bm, __shfl_xor(bm, 4));
    bm = fmaxf(bm, __shfl_xor(bm, 8));
    bm = fmaxf(bm, __shfl_xor(bm, 16));
    bm = fmaxf(bm, __shfl_xor(bm, 32));
    if ((t & 63) == 0) wmaxL[w] = bm;
    __syncthreads();
    if (t == 0) {
      float b2 = fmaxf(fmaxf(wmaxL[0], wmaxL[1]), fmaxf(wmaxL[2], wmaxL[3]));
      unsigned ub = __float_as_uint(b2);
      ub = (ub & 0x80000000u) ? ~ub : (ub | 0x80000000u);
      atomicMax(kmaxU + (int)(row0 >> 12), ub);
    }
  }
}

// ---------------------------------------------------------------------------
// K4: per-chunk sums (validated r5 tiling); phi_k = fma(E, sR, epsR) now.
// ---------------------------------------------------------------------------
__device__ __forceinline__ int phi_col(int m) { return m + 4 * ((m >> 4) & 7); }

__global__ __launch_bounds__(256, 2) void k_chunk(const float* __restrict__ Eb,
                                                  const float* __restrict__ v,
                                                  const unsigned* __restrict__ kmaxU,
                                                  float* __restrict__ Sc,
                                                  float* __restrict__ zc) {
  __shared__ __align__(16) float phE[16][284];
  __shared__ __align__(16) float vT[16][68];

  const int t = threadIdx.x;
  const int bh = blockIdx.x >> 5;
  const int c = blockIdx.x & 31;
  const float sR = kRatio * __expf(-dec_max(kmaxU[bh]));
  const float epsR = kRatio * kEpsK;
  const long rowbase = (long)bh * kN + (long)c * kC;
  const float* Ep = Eb + rowbase * kM;
  const float* vp = v + rowbase * kE;

  const int et = t & 15, mg = t >> 4;
  const int e0 = 4 * et, m0 = 16 * mg;
  const int pcol = phi_col(m0);

  float acc[16][4];
#pragma unroll
  for (int i = 0; i < 16; ++i)
#pragma unroll
    for (int u = 0; u < 4; ++u) acc[i][u] = 0.f;
  float zsum = 0.f;

  for (int rt = 0; rt < 8; ++rt) {
    __syncthreads();
#pragma unroll
    for (int i = 0; i < 4; ++i) {
      const int flat = i * 256 + t;
      const int rr = flat >> 6;
      const int m4 = (flat & 63) * 4;
      float4 xx = *reinterpret_cast<const float4*>(
          &Ep[(long)(rt * 16 + rr) * kM + m4]);
      float4 ph;
      ph.x = fmaf(xx.x, sR, epsR);
      ph.y = fmaf(xx.y, sR, epsR);
      ph.z = fmaf(xx.z, sR, epsR);
      ph.w = fmaf(xx.w, sR, epsR);
      *reinterpret_cast<float4*>(&phE[rr][phi_col(m4)]) = ph;
    }
    {
      const int rr = t >> 4, ee = (t & 15) * 4;
      float4 vv = *reinterpret_cast<const float4*>(
          &vp[(long)(rt * 16 + rr) * kE + ee]);
      *reinterpret_cast<float4*>(&vT[rr][ee]) = vv;
    }
    __syncthreads();

    for (int r = 0; r < 16; ++r) {
      float4 bv = *reinterpret_cast<const float4*>(&vT[r][e0]);
      float pv[16];
#pragma unroll
      for (int a = 0; a < 4; ++a) {
        float4 p4 = *reinterpret_cast<const float4*>(&phE[r][pcol + 4 * a]);
        pv[4 * a + 0] = p4.x; pv[4 * a + 1] = p4.y;
        pv[4 * a + 2] = p4.z; pv[4 * a + 3] = p4.w;
      }
#pragma unroll
      for (int i = 0; i < 16; ++i) {
        acc[i][0] = fmaf(pv[i], bv.x, acc[i][0]);
        acc[i][1] = fmaf(pv[i], bv.y, acc[i][1]);
        acc[i][2] = fmaf(pv[i], bv.z, acc[i][2]);
        acc[i][3] = fmaf(pv[i], bv.w, acc[i][3]);
      }
    }
    {
      const int zcol = phi_col(t);
      float zp = 0.f;
#pragma unroll
      for (int r = 0; r < 16; ++r) zp += phE[r][zcol];
      zsum += zp;
    }
  }

  float* scp = Sc + (long)(bh * kNC + c) * (kM * kE);
#pragma unroll
  for (int i = 0; i < 16; ++i) {
    float4 o = make_float4(acc[i][0], acc[i][1], acc[i][2], acc[i][3]);
    *reinterpret_cast<float4*>(&scp[(long)(m0 + i) * kE + e0]) = o;
  }
  zc[(long)(bh * kNC + c) * kM + t] = zsum;
}

// ---------------------------------------------------------------------------
// K4b: exclusive prefix over 32 chunks; float4 S path.
// ---------------------------------------------------------------------------
__global__ __launch_bounds__(256) void k_prefix(float* __restrict__ Sc,
                                                float* __restrict__ zc) {
  const int bid = blockIdx.x;
  if (bid < 256) {
    const int bh = bid >> 4;
    const int f4 = (bid & 15) * 256 + threadIdx.x;  // 0..4095
    float4* base = reinterpret_cast<float4*>(Sc) + (long)bh * kNC * 4096 + f4;
    float4 run = make_float4(0.f, 0.f, 0.f, 0.f);
#pragma unroll 4
    for (int c = 0; c < kNC; ++c) {
      float4 tmp = base[(long)c * 4096];
      base[(long)c * 4096] = run;
      run.x += tmp.x; run.y += tmp.y; run.z += tmp.z; run.w += tmp.w;
    }
  } else {
    const int bh = bid - 256;
    const int m = threadIdx.x;
    long base = (long)bh * kNC * kM + m;
    float run = 0.f;
    for (int c = 0; c < kNC; ++c) {
      float tmp = zc[base + (long)c * kM];
      zc[base + (long)c * kM] = run;
      run += tmp;
    }
  }
}

// ---------------------------------------------------------------------------
// K5 r6: phase 1 = split-bf16 MFMA (scores 128x128xK256, inter 128x(64+ze)xK256)
//        phase 2 = r5's fp32 VALU intra + epilogue via LDS bridges.
// 4 waves; wave w owns rows w*32..w*32+31 (2 row-tiles of 16).
// ---------------------------------------------------------------------------
constexpr int kPadAB = 40;  // bf16 cols for [*][32] tiles (80B rows: bank-balanced)
constexpr int kPadSC = 69;  // f32 score half cols (r5 layout)
constexpr int kPadIT = 68;  // f32 inter cols

struct PA_t {
  unsigned short Aqh[128][kPadAB], Aql[128][kPadAB];  // phi_q hi/lo  [row][m]
  unsigned short Bkh[128][kPadAB], Bkl[128][kPadAB];  // phi_k hi/lo  [kcol][m]
  unsigned short Sh[80][kPadAB], Sl[80][kPadAB];      // S^T hi/lo    [e][m]; e=64 -> ze
};
struct PB_t {
  float sc[kC][kPadSC];     // masked scores half  [r][k2]
  float inter[kC][kPadIT];  // inter results       [r][e]
  float den[kC];            // dena (phi_q . (z_prev+eps))
};
union SmemV { PA_t a; PB_t b; };

__global__ __launch_bounds__(256, 2) void k_out(const float* __restrict__ phiq,
                                                const float* __restrict__ Eb,
                                                const float* __restrict__ v,
                                                const float* __restrict__ Sc,
                                                const float* __restrict__ zc,
                                                const unsigned* __restrict__ kmaxU,
                                                float* __restrict__ outp) {
  __shared__ __align__(16) SmemV sm;

  const int t = threadIdx.x;
  const int l15 = t & 15;
  const int g = (t >> 4) & 3;  // k-group within wave
  const int w = t >> 6;
  const int rbase = w * 32;
  const int bh = blockIdx.x >> 5;
  const int c = blockIdx.x & 31;
  const float mx = dec_max(kmaxU[bh]);
  const float sR = kRatio * __expf(-mx);
  const float epsR = kRatio * kEpsK;

  const long row0 = (long)bh * kN + (long)c * kC;
  const float* phiq_p = phiq + row0 * kM;
  const float* E_p = Eb + row0 * kM;
  const float* v_p = v + row0 * kE;
  const float* S_p = Sc + (long)(bh * kNC + c) * (kM * kE);
  const float* z_p = zc + (long)(bh * kNC + c) * kM;

  // zero S rows 65..79 once (read by the et=4 tile; only row 64 = ze nonzero)
  for (int idx = t; idx < 480; idx += 256) {
    const int r = 65 + (idx >> 5), m = idx & 31;
    sm.a.Sh[r][m] = 0; sm.a.Sl[r][m] = 0;
  }

  f4v accS[2][8];
  f4v accI[2][5];
#pragma unroll
  for (int rt = 0; rt < 2; ++rt) {
#pragma unroll
    for (int ct = 0; ct < 8; ++ct) accS[rt][ct] = (f4v){0.f, 0.f, 0.f, 0.f};
#pragma unroll
    for (int et = 0; et < 5; ++et) accI[rt][et] = (f4v){0.f, 0.f, 0.f, 0.f};
  }

  // ---- phase 1: K-loop over m (8 steps of 32) ----
  for (int mt = 0; mt < 8; ++mt) {
    __syncthreads();
    // stage phi_q / phi_k tiles [128][32] as bf16 hi+lo
#pragma unroll
    for (int i = 0; i < 4; ++i) {
      const int f = i * 256 + t;
      const int row = f >> 3, mq = (f & 7) * 4;
      float4 xq = *reinterpret_cast<const float4*>(&phiq_p[(long)row * kM + mt * 32 + mq]);
      ushort4 h, lo;
      h.x = f2bf(xq.x); lo.x = f2bf(xq.x - bf2f(h.x));
      h.y = f2bf(xq.y); lo.y = f2bf(xq.y - bf2f(h.y));
      h.z = f2bf(xq.z); lo.z = f2bf(xq.z - bf2f(h.z));
      h.w = f2bf(xq.w); lo.w = f2bf(xq.w - bf2f(h.w));
      *reinterpret_cast<ushort4*>(&sm.a.Aqh[row][mq]) = h;
      *reinterpret_cast<ushort4*>(&sm.a.Aql[row][mq]) = lo;
      float4 xe = *reinterpret_cast<const float4*>(&E_p[(long)row * kM + mt * 32 + mq]);
      float4 pk;
      pk.x = fmaf(xe.x, sR, epsR); pk.y = fmaf(xe.y, sR, epsR);
      pk.z = fmaf(xe.z, sR, epsR); pk.w = fmaf(xe.w, sR, epsR);
      h.x = f2bf(pk.x); lo.x = f2bf(pk.x - bf2f(h.x));
      h.y = f2bf(pk.y); lo.y = f2bf(pk.y - bf2f(h.y));
      h.z = f2bf(pk.z); lo.z = f2bf(pk.z - bf2f(h.z));
      h.w = f2bf(pk.w); lo.w = f2bf(pk.w - bf2f(h.w));
      *reinterpret_cast<ushort4*>(&sm.a.Bkh[row][mq]) = h;
      *reinterpret_cast<ushort4*>(&sm.a.Bkl[row][mq]) = lo;
    }
    // stage S^T tile [e][m] (transpose) hi+lo
#pragma unroll
    for (int i = 0; i < 2; ++i) {
      const int f = i * 256 + t;
      const int ml = f >> 4, e4 = (f & 15) * 4;
      float4 sv = *reinterpret_cast<const float4*>(&S_p[(long)(mt * 32 + ml) * kE + e4]);
      unsigned short hh;
      hh = f2bf(sv.x); sm.a.Sh[e4 + 0][ml] = hh; sm.a.Sl[e4 + 0][ml] = f2bf(sv.x - bf2f(hh));
      hh = f2bf(sv.y); sm.a.Sh[e4 + 1][ml] = hh; sm.a.Sl[e4 + 1][ml] = f2bf(sv.y - bf2f(hh));
      hh = f2bf(sv.z); sm.a.Sh[e4 + 2][ml] = hh; sm.a.Sl[e4 + 2][ml] = f2bf(sv.z - bf2f(hh));
      hh = f2bf(sv.w); sm.a.Sh[e4 + 3][ml] = hh; sm.a.Sl[e4 + 3][ml] = f2bf(sv.w - bf2f(hh));
    }
    if (t < 32) {  // ze column -> S row 64
      float zez = z_p[mt * 32 + t] + kEpsD;
      unsigned short hh = f2bf(zez);
      sm.a.Sh[64][t] = hh; sm.a.Sl[64][t] = f2bf(zez - bf2f(hh));
    }
    __syncthreads();

    s8v aqh[2], aql[2];
#pragma unroll
    for (int rt = 0; rt < 2; ++rt) {
      aqh[rt] = *reinterpret_cast<const s8v*>(&sm.a.Aqh[rbase + rt * 16 + l15][g * 8]);
      aql[rt] = *reinterpret_cast<const s8v*>(&sm.a.Aql[rbase + rt * 16 + l15][g * 8]);
    }
#pragma unroll
    for (int ct = 0; ct < 8; ++ct) {
      s8v bh_ = *reinterpret_cast<const s8v*>(&sm.a.Bkh[ct * 16 + l15][g * 8]);
      s8v bl_ = *reinterpret_cast<const s8v*>(&sm.a.Bkl[ct * 16 + l15][g * 8]);
#pragma unroll
      for (int rt = 0; rt < 2; ++rt) {
        accS[rt][ct] = __builtin_amdgcn_mfma_f32_16x16x32_bf16(aqh[rt], bh_, accS[rt][ct], 0, 0, 0);
        accS[rt][ct] = __builtin_amdgcn_mfma_f32_16x16x32_bf16(aqh[rt], bl_, accS[rt][ct], 0, 0, 0);
        accS[rt][ct] = __builtin_amdgcn_mfma_f32_16x16x32_bf16(aql[rt], bh_, accS[rt][ct], 0, 0, 0);
      }
    }
#pragma unroll
    for (int et = 0; et < 5; ++et) {
      s8v sh_ = *reinterpret_cast<const s8v*>(&sm.a.Sh[et * 16 + l15][g * 8]);
      s8v sl_ = *reinterpret_cast<const s8v*>(&sm.a.Sl[et * 16 + l15][g * 8]);
#pragma unroll
      for (int rt = 0; rt < 2; ++rt) {
        accI[rt][et] = __builtin_amdgcn_mfma_f32_16x16x32_bf16(aqh[rt], sh_, accI[rt][et], 0, 0, 0);
        accI[rt][et] = __builtin_amdgcn_mfma_f32_16x16x32_bf16(aqh[rt], sl_, accI[rt][et], 0, 0, 0);
        accI[rt][et] = __builtin_amdgcn_mfma_f32_16x16x32_bf16(aql[rt], sh_, accI[rt][et], 0, 0, 0);
      }
    }
  }
  __syncthreads();  // phase-A LDS dead -> PB (union) writable

  // bridge inter + den to LDS (D-frag: row=(lane>>4)*4+reg, col=lane&15)
#pragma unroll
  for (int rt = 0; rt < 2; ++rt) {
#pragma unroll
    for (int et = 0; et < 4; ++et) {
      f4v vv = accI[rt][et];
#pragma unroll
      for (int reg = 0; reg < 4; ++reg)
        sm.b.inter[rbase + rt * 16 + g * 4 + reg][et * 16 + l15] = vv[reg];
    }
    if (l15 == 0) {
      f4v dv = accI[rt][4];
#pragma unroll
      for (int reg = 0; reg < 4; ++reg)
        sm.b.den[rbase + rt * 16 + g * 4 + reg] = dv[reg];
    }
  }

  // ---- phase 2: r5's fp32 intra (half-wise through sc LDS) ----
  const int tr = t >> 4;
  const int tc = t & 15;
  const int r0 = tr * 8;
  const int e0 = tc * 4;

  float intra_[8][4];
  float denb[8];
#pragma unroll
  for (int i = 0; i < 8; ++i) {
    denb[i] = 0.f;
#pragma unroll
    for (int jj = 0; jj < 4; ++jj) intra_[i][jj] = 0.f;
  }

#pragma unroll
  for (int half = 0; half < 2; ++half) {
    __syncthreads();
    // masked score write from MFMA D-frags
#pragma unroll
    for (int cti = 0; cti < 4; ++cti) {
      const int ct = half * 4 + cti;
#pragma unroll
      for (int rt = 0; rt < 2; ++rt) {
        f4v vv = accS[rt][ct];
#pragma unroll
        for (int reg = 0; reg < 4; ++reg) {
          const int r = rbase + rt * 16 + g * 4 + reg;
          const int cg = ct * 16 + l15;
          sm.b.sc[r][cti * 16 + l15] = (cg <= r) ? vv[reg] : 0.f;
        }
      }
    }
    __syncthreads();
    const float* vh = v_p + (long)half * 64 * kE;
    for (int k2 = 0; k2 < 64; ++k2) {
      float as[8];
#pragma unroll
      for (int i = 0; i < 8; ++i) as[i] = sm.b.sc[r0 + i][k2];
      const float4 vv = *reinterpret_cast<const float4*>(vh + (long)k2 * kE + e0);
#pragma unroll
      for (int i = 0; i < 8; ++i) {
        denb[i] += as[i];
        intra_[i][0] = fmaf(as[i], vv.x, intra_[i][0]);
        intra_[i][1] = fmaf(as[i], vv.y, intra_[i][1]);
        intra_[i][2] = fmaf(as[i], vv.z, intra_[i][2]);
        intra_[i][3] = fmaf(as[i], vv.w, intra_[i][3]);
      }
    }
  }

  float* op = outp + row0 * kE;
#pragma unroll
  for (int i = 0; i < 8; ++i) {
    const float4 itv = *reinterpret_cast<const float4*>(&sm.b.inter[r0 + i][e0]);
    const float dinv = 1.0f / (sm.b.den[r0 + i] + denb[i]);
    float4 o;
    o.x = (itv.x + intra_[i][0]) * dinv;
    o.y = (itv.y + intra_[i][1]) * dinv;
    o.z = (itv.z + intra_[i][2]) * dinv;
    o.w = (itv.w + intra_[i][3]) * dinv;
    *reinterpret_cast<float4*>(op + (long)(r0 + i) * kE + e0) = o;
  }
}

// ---------------------------------------------------------------------------
extern "C" void kernel_launch(void* const* d_in, const int* in_sizes, int n_in,
                              void* d_out, int out_size, void* d_ws, size_t ws_size,
                              hipStream_t stream) {
  const float* q = (const float*)d_in[0];
  const float* k = (const float*)d_in[1];
  const float* v = (const float*)d_in[2];
  const float* proj = (const float*)d_in[3];
  float* out = (float*)d_out;
  float* ws = (float*)d_ws;

  float* phiq = ws;                               // 16,777,216
  float* Eb = ws + 16777216L;                     // 16,777,216  (exp(dd-diag) for k)
  float* Sc = ws + 33554432L;                     // 8,388,608
  float* zc = ws + 41943040L;                     // 131,072
  unsigned* kmaxU = (unsigned*)(ws + 42074112L);  // 16

  hipMemsetAsync(kmaxU, 0, kBH * sizeof(unsigned), stream);
  k_proj<true><<<dim3(1024), dim3(256), 0, stream>>>(q, proj, phiq, nullptr);
  k_proj<false><<<dim3(1024), dim3(256), 0, stream>>>(k, proj, Eb, kmaxU);
  k_chunk<<<dim3(512), dim3(256), 0, stream>>>(Eb, v, kmaxU, Sc, zc);
  k_prefix<<<dim3(272), dim3(256), 0, stream>>>(Sc, zc);
  k_out<<<dim3(512), dim3(256), 0, stream>>>(phiq, Eb, v, Sc, zc, kmaxU, out);
}